// Round 1
// baseline (221.791 us; speedup 1.0000x reference)
//
#include <hip/hip_runtime.h>
#include <hip/hip_fp16.h>

#define Bsz   256
#define Nn    1152
#define ICc   8
#define Kk    10
#define OCc   16
#define NT    576      // threads per block (9 waves)
#define NW    9
#define INV_N (1.0f/1152.0f)

// One block per (k, pair of b). LDS holds u_hat (fp16, transposed+swizzled) for
// both b; 3 routing iterations run entirely from LDS.
// LDS total ~79.7 KB -> 2 blocks/CU (overlap W-stream of one block with
// routing VALU of the other).
__global__ __launch_bounds__(NT, 5)
void digitcaps_kernel(const float* __restrict__ u,
                      const float* __restrict__ W,
                      float* __restrict__ out)
{
    const int t    = threadIdx.x;
    const int lane = t & 63;
    const int wav  = t >> 6;
    const int blk  = blockIdx.x;
    const int k    = blk >> 7;      // 0..9   (k-major: same-k blocks cluster per XCD)
    const int bg   = blk & 127;     // 0..127
    const int b0   = bg * 2;

    // u_hat layout: uhS[b*8*Nn + j*Nn + (n ^ (8*(j&3)))] = half2(uh[n][2j], uh[n][2j+1])
    __shared__ __half2 uhS[2 * 8 * Nn];   // 73728 B
    __shared__ __half  cS[2 * Nn];        // 4608 B  coupling coeffs
    __shared__ float   redS[2 * NW * 16]; // 1152 B  s-reduction partials
    __shared__ float   vS[2 * 16];        // 128 B   current v
    __shared__ float   scalS[2 * NW];     // 72 B    softmax wave partials
    __shared__ float   bcS[2];            // 8 B     broadcast scalars

    // ---------------- Phase 1: u_hat = u . W  (fp32 compute, fp16 store) ----
    #pragma unroll
    for (int r = 0; r < 2; ++r) {
        const int n = t + r * NT;
        const float4* up0 = (const float4*)(u + ((size_t)b0 * Nn + n) * ICc);
        const float4* up1 = (const float4*)(u + ((size_t)(b0 + 1) * Nn + n) * ICc);
        const float4 ua0 = up0[0], ua1 = up0[1];
        const float4 ub0 = up1[0], ub1 = up1[1];
        const float ua[8] = {ua0.x,ua0.y,ua0.z,ua0.w, ua1.x,ua1.y,ua1.z,ua1.w};
        const float ub[8] = {ub0.x,ub0.y,ub0.z,ub0.w, ub1.x,ub1.y,ub1.z,ub1.w};
        const float4* wp = (const float4*)(W + ((size_t)k * Nn + n) * (ICc * OCc));
        float a0[16], a1[16];
        #pragma unroll
        for (int o = 0; o < 16; ++o) { a0[o] = 0.f; a1[o] = 0.f; }
        #pragma unroll
        for (int i = 0; i < 8; ++i) {
            const float4 w0 = wp[i*4+0], w1 = wp[i*4+1];
            const float4 w2 = wp[i*4+2], w3 = wp[i*4+3];
            const float wv[16] = {w0.x,w0.y,w0.z,w0.w, w1.x,w1.y,w1.z,w1.w,
                                  w2.x,w2.y,w2.z,w2.w, w3.x,w3.y,w3.z,w3.w};
            const float x = ua[i], y = ub[i];
            #pragma unroll
            for (int o = 0; o < 16; ++o) { a0[o] += x * wv[o]; a1[o] += y * wv[o]; }
        }
        #pragma unroll
        for (int j = 0; j < 8; ++j) {
            const int idx = j * Nn + (n ^ (8 * (j & 3)));
            uhS[idx]          = __floats2half2_rn(a0[2*j], a0[2*j+1]);
            uhS[8*Nn + idx]   = __floats2half2_rn(a1[2*j], a1[2*j+1]);
        }
    }
    __syncthreads();

    // ---------------- Phase 2: routing ----------------
    float lg0[2] = {0.f, 0.f};    // logits for rows n=t, n=t+NT  (b0)
    float lg1[2] = {0.f, 0.f};    // (b0+1)

    const int j_s = lane & 7;     // o-pair handled by this lane in s-pass
    const int g_s = lane >> 3;    // row group
    const int swz = 8 * (j_s & 3);

    for (int it = 0; it < 3; ++it) {
        // ---- s-pass: s[o] = sum_n c[n]*u_hat[n][o]  (o-distributed lanes) ----
        float2 sp0 = {0.f, 0.f}, sp1 = {0.f, 0.f};
        #pragma unroll
        for (int cc = 0; cc < 16; ++cc) {
            const int n = cc * 72 + wav * 8 + g_s;
            float c0, c1;
            if (it == 0) { c0 = INV_N; c1 = INV_N; }
            else { c0 = __half2float(cS[n]); c1 = __half2float(cS[Nn + n]); }
            const int idx = j_s * Nn + (n ^ swz);
            const float2 f0 = __half22float2(uhS[idx]);
            const float2 f1 = __half22float2(uhS[8*Nn + idx]);
            sp0.x += c0 * f0.x; sp0.y += c0 * f0.y;
            sp1.x += c1 * f1.x; sp1.y += c1 * f1.y;
        }
        #pragma unroll
        for (int off = 8; off <= 32; off <<= 1) {
            sp0.x += __shfl_xor(sp0.x, off);
            sp0.y += __shfl_xor(sp0.y, off);
            sp1.x += __shfl_xor(sp1.x, off);
            sp1.y += __shfl_xor(sp1.y, off);
        }
        if (lane < 8) {
            redS[(0*NW + wav)*16 + 2*j_s    ] = sp0.x;
            redS[(0*NW + wav)*16 + 2*j_s + 1] = sp0.y;
            redS[(1*NW + wav)*16 + 2*j_s    ] = sp1.x;
            redS[(1*NW + wav)*16 + 2*j_s + 1] = sp1.y;
        }
        __syncthreads();

        // ---- finalize s + squash on wave 0 ----
        if (t < 32) {
            const int b = t >> 4, o = t & 15;
            float s = 0.f;
            #pragma unroll
            for (int w = 0; w < NW; ++w) s += redS[(b*NW + w)*16 + o];
            float s2 = s * s;
            #pragma unroll
            for (int off = 1; off <= 8; off <<= 1) s2 += __shfl_xor(s2, off);
            const float scale = (s2 / (1.f + s2)) * rsqrtf(fmaxf(s2, 1e-30f));
            const float v = s * scale;
            vS[b*16 + o] = v;
            if (it == 2) out[((size_t)k * Bsz + b0 + b) * OCc + o] = v;
        }
        __syncthreads();
        if (it == 2) break;

        // ---- a-pass: logits += u_hat . v  (row-distributed) ----
        float v0[16], v1[16];
        #pragma unroll
        for (int o = 0; o < 16; ++o) { v0[o] = vS[o]; v1[o] = vS[16 + o]; }
        #pragma unroll
        for (int r = 0; r < 2; ++r) {
            const int n = t + r * NT;
            float acc0 = 0.f, acc1 = 0.f;
            #pragma unroll
            for (int j = 0; j < 8; ++j) {
                const int idx = j * Nn + (n ^ (8 * (j & 3)));
                const float2 f0 = __half22float2(uhS[idx]);
                const float2 f1 = __half22float2(uhS[8*Nn + idx]);
                acc0 += f0.x * v0[2*j] + f0.y * v0[2*j+1];
                acc1 += f1.x * v1[2*j] + f1.y * v1[2*j+1];
            }
            lg0[r] += acc0;
            lg1[r] += acc1;
        }

        // ---- softmax over n (per b): block max, then sum of exp ----
        float m0 = fmaxf(lg0[0], lg0[1]);
        float m1 = fmaxf(lg1[0], lg1[1]);
        #pragma unroll
        for (int off = 1; off <= 32; off <<= 1) {
            m0 = fmaxf(m0, __shfl_xor(m0, off));
            m1 = fmaxf(m1, __shfl_xor(m1, off));
        }
        if (lane == 0) { scalS[wav] = m0; scalS[NW + wav] = m1; }
        __syncthreads();
        if (t < 2) {
            float m = scalS[t*NW];
            for (int w = 1; w < NW; ++w) m = fmaxf(m, scalS[t*NW + w]);
            bcS[t] = m;
        }
        __syncthreads();
        m0 = bcS[0]; m1 = bcS[1];
        const float e00 = __expf(lg0[0] - m0), e01 = __expf(lg0[1] - m0);
        const float e10 = __expf(lg1[0] - m1), e11 = __expf(lg1[1] - m1);
        float t0 = e00 + e01, t1 = e10 + e11;
        #pragma unroll
        for (int off = 1; off <= 32; off <<= 1) {
            t0 += __shfl_xor(t0, off);
            t1 += __shfl_xor(t1, off);
        }
        __syncthreads();   // all threads read bcS(max) already; safe to reuse scalS/bcS
        if (lane == 0) { scalS[wav] = t0; scalS[NW + wav] = t1; }
        __syncthreads();
        if (t < 2) {
            float d = 0.f;
            for (int w = 0; w < NW; ++w) d += scalS[t*NW + w];
            bcS[t] = 1.0f / d;
        }
        __syncthreads();
        const float rd0 = bcS[0], rd1 = bcS[1];
        cS[t]           = __float2half(e00 * rd0);
        cS[t + NT]      = __float2half(e01 * rd0);
        cS[Nn + t]      = __float2half(e10 * rd1);
        cS[Nn + t + NT] = __float2half(e11 * rd1);
        __syncthreads();
    }
}

extern "C" void kernel_launch(void* const* d_in, const int* in_sizes, int n_in,
                              void* d_out, int out_size, void* d_ws, size_t ws_size,
                              hipStream_t stream) {
    const float* u = (const float*)d_in[0];
    const float* W = (const float*)d_in[1];
    float* out = (float*)d_out;
    digitcaps_kernel<<<dim3(Kk * (Bsz / 2)), dim3(NT), 0, stream>>>(u, W, out);
}

// Round 2
// 160.682 us; speedup vs baseline: 1.3803x; 1.3803x over previous
//
#include <hip/hip_runtime.h>
#include <hip/hip_fp16.h>

#define Bsz   256
#define Nn    1152
#define Kk    10
#define OCc   16
#define NT    576      // threads per block (9 waves)
#define NW    9
#define INV_N (1.0f/1152.0f)

__device__ __forceinline__ unsigned pkh2(float x, float y) {
    __half2 h = __floats2half2_rn(x, y);
    return *reinterpret_cast<unsigned*>(&h);
}
__device__ __forceinline__ float2 uph2(unsigned v) {
    __half2 h = *reinterpret_cast<__half2*>(&v);
    return __half22float2(h);
}

// One block per (k, pair of b). u_hat in LDS as fp16, b0/b1 interleaved in
// uint2 (-> ds_read_b64), layout uhS[j*Nn + (n ^ 8*(j&1))] for o-pair j.
// Phase 1: thread pair (t&1) splits the 16 o's -> ~50 live VGPRs, no spills,
// adjacent lanes cover full 64B W lines, W read once per block.
__global__ __launch_bounds__(NT, 2)
void digitcaps_kernel(const float* __restrict__ u,
                      const float* __restrict__ W,
                      float* __restrict__ out)
{
    const int t    = threadIdx.x;
    const int lane = t & 63;
    const int wav  = t >> 6;
    const int blk  = blockIdx.x;
    const int k    = blk >> 7;      // 0..9
    const int bg   = blk & 127;     // 0..127
    const int b0   = bg * 2;

    __shared__ uint2    uhS[8 * Nn];        // 73728 B  {half2(b0 o-pair), half2(b1 o-pair)}
    __shared__ unsigned cS2[Nn];            // 4608 B   half2(c_b0, c_b1) per n
    __shared__ float    redS[2 * NW * 16];  // 1152 B
    __shared__ __align__(16) float vS[32];  // 128 B
    __shared__ float    scalS[2 * NW];      // 72 B
    __shared__ float    bcS[2];             // 8 B

    // ---------------- Phase 1: u_hat = u . W ----------------
    {
        const int oh   = t & 1;      // which o-half (o = 8*oh .. 8*oh+7)
        const int nsub = t >> 1;     // 0..287
        for (int r = 0; r < 4; ++r) {
            const int n = r * 288 + nsub;
            const float4* up0 = (const float4*)(u + ((size_t)b0 * Nn + n) * 8);
            const float4* up1 = (const float4*)(u + ((size_t)(b0 + 1) * Nn + n) * 8);
            const float4 x0 = up0[0], x1 = up0[1];
            const float4 y0 = up1[0], y1 = up1[1];
            const float ua[8] = {x0.x,x0.y,x0.z,x0.w, x1.x,x1.y,x1.z,x1.w};
            const float ub[8] = {y0.x,y0.y,y0.z,y0.w, y1.x,y1.y,y1.z,y1.w};
            // W row for n: 128 floats = 32 float4; this thread's half: i*4 + oh*2 + {0,1}
            const float4* wp = (const float4*)(W + ((size_t)k * Nn + n) * 128) + oh * 2;
            float a0[8], a1[8];
            #pragma unroll
            for (int o = 0; o < 8; ++o) { a0[o] = 0.f; a1[o] = 0.f; }
            #pragma unroll
            for (int i = 0; i < 8; ++i) {
                const float4 w0 = wp[i*4 + 0];
                const float4 w1 = wp[i*4 + 1];
                const float wv[8] = {w0.x,w0.y,w0.z,w0.w, w1.x,w1.y,w1.z,w1.w};
                const float x = ua[i], y = ub[i];
                #pragma unroll
                for (int o = 0; o < 8; ++o) { a0[o] += x * wv[o]; a1[o] += y * wv[o]; }
            }
            #pragma unroll
            for (int jj = 0; jj < 4; ++jj) {
                const int j = oh * 4 + jj;               // o-pair index 0..7 (j&1 == jj&1)
                const int idx = j * Nn + (n ^ (8 * (j & 1)));
                uhS[idx] = make_uint2(pkh2(a0[2*jj], a0[2*jj+1]),
                                      pkh2(a1[2*jj], a1[2*jj+1]));
            }
        }
    }
    __syncthreads();

    // ---------------- Phase 2: routing ----------------
    float lg0[2] = {0.f, 0.f};    // logits rows n=t, n=t+NT (b0)
    float lg1[2] = {0.f, 0.f};    // (b0+1)

    const int j_s = lane & 7;
    const int g_s = lane >> 3;
    const int swz = 8 * (j_s & 1);

    for (int it = 0; it < 3; ++it) {
        // ---- s-pass ----
        float2 sp0 = {0.f, 0.f}, sp1 = {0.f, 0.f};
        #pragma unroll
        for (int cc = 0; cc < 16; ++cc) {
            const int n = cc * 72 + wav * 8 + g_s;
            float2 c2;
            if (it == 0) { c2.x = INV_N; c2.y = INV_N; }
            else          c2 = uph2(cS2[n]);
            const uint2 q = uhS[j_s * Nn + (n ^ swz)];
            const float2 f0 = uph2(q.x);
            const float2 f1 = uph2(q.y);
            sp0.x += c2.x * f0.x; sp0.y += c2.x * f0.y;
            sp1.x += c2.y * f1.x; sp1.y += c2.y * f1.y;
        }
        #pragma unroll
        for (int off = 8; off <= 32; off <<= 1) {
            sp0.x += __shfl_xor(sp0.x, off);
            sp0.y += __shfl_xor(sp0.y, off);
            sp1.x += __shfl_xor(sp1.x, off);
            sp1.y += __shfl_xor(sp1.y, off);
        }
        if (lane < 8) {
            redS[(0*NW + wav)*16 + 2*j_s    ] = sp0.x;
            redS[(0*NW + wav)*16 + 2*j_s + 1] = sp0.y;
            redS[(1*NW + wav)*16 + 2*j_s    ] = sp1.x;
            redS[(1*NW + wav)*16 + 2*j_s + 1] = sp1.y;
        }
        __syncthreads();

        // ---- finalize s + squash on wave 0 ----
        if (t < 32) {
            const int b = t >> 4, o = t & 15;
            float s = 0.f;
            #pragma unroll
            for (int w = 0; w < NW; ++w) s += redS[(b*NW + w)*16 + o];
            float s2 = s * s;
            #pragma unroll
            for (int off = 1; off <= 8; off <<= 1) s2 += __shfl_xor(s2, off);
            const float scale = (s2 / (1.f + s2)) * rsqrtf(fmaxf(s2, 1e-30f));
            const float v = s * scale;
            vS[b*16 + o] = v;
            if (it == 2) out[((size_t)k * Bsz + b0 + b) * OCc + o] = v;
        }
        __syncthreads();
        if (it == 2) break;

        // ---- a-pass: logits += u_hat . v ----
        float v0[16], v1[16];
        {
            const float4* vp = (const float4*)vS;
            #pragma unroll
            for (int q4 = 0; q4 < 4; ++q4) {
                *(float4*)&v0[4*q4] = vp[q4];
                *(float4*)&v1[4*q4] = vp[4 + q4];
            }
        }
        #pragma unroll
        for (int r = 0; r < 2; ++r) {
            const int n = t + r * NT;
            float acc0 = 0.f, acc1 = 0.f;
            #pragma unroll
            for (int j = 0; j < 8; ++j) {
                const uint2 q = uhS[j * Nn + (n ^ (8 * (j & 1)))];
                const float2 f0 = uph2(q.x);
                const float2 f1 = uph2(q.y);
                acc0 += f0.x * v0[2*j] + f0.y * v0[2*j+1];
                acc1 += f1.x * v1[2*j] + f1.y * v1[2*j+1];
            }
            lg0[r] += acc0;
            lg1[r] += acc1;
        }

        // ---- softmax over n (per b) ----
        float m0 = fmaxf(lg0[0], lg0[1]);
        float m1 = fmaxf(lg1[0], lg1[1]);
        #pragma unroll
        for (int off = 1; off <= 32; off <<= 1) {
            m0 = fmaxf(m0, __shfl_xor(m0, off));
            m1 = fmaxf(m1, __shfl_xor(m1, off));
        }
        if (lane == 0) { scalS[wav] = m0; scalS[NW + wav] = m1; }
        __syncthreads();
        if (t < 2) {
            float m = scalS[t*NW];
            for (int w = 1; w < NW; ++w) m = fmaxf(m, scalS[t*NW + w]);
            bcS[t] = m;
        }
        __syncthreads();
        m0 = bcS[0]; m1 = bcS[1];
        const float e00 = __expf(lg0[0] - m0), e01 = __expf(lg0[1] - m0);
        const float e10 = __expf(lg1[0] - m1), e11 = __expf(lg1[1] - m1);
        float t0 = e00 + e01, t1 = e10 + e11;
        #pragma unroll
        for (int off = 1; off <= 32; off <<= 1) {
            t0 += __shfl_xor(t0, off);
            t1 += __shfl_xor(t1, off);
        }
        __syncthreads();
        if (lane == 0) { scalS[wav] = t0; scalS[NW + wav] = t1; }
        __syncthreads();
        if (t < 2) {
            float d = 0.f;
            for (int w = 0; w < NW; ++w) d += scalS[t*NW + w];
            bcS[t] = 1.0f / d;
        }
        __syncthreads();
        const float rd0 = bcS[0], rd1 = bcS[1];
        cS2[t]      = pkh2(e00 * rd0, e10 * rd1);   // n = t
        cS2[t + NT] = pkh2(e01 * rd0, e11 * rd1);   // n = t + 576
        __syncthreads();
    }
}

extern "C" void kernel_launch(void* const* d_in, const int* in_sizes, int n_in,
                              void* d_out, int out_size, void* d_ws, size_t ws_size,
                              hipStream_t stream) {
    const float* u = (const float*)d_in[0];
    const float* W = (const float*)d_in[1];
    float* out = (float*)d_out;
    digitcaps_kernel<<<dim3(Kk * (Bsz / 2)), dim3(NT), 0, stream>>>(u, W, out);
}

// Round 3
// 130.362 us; speedup vs baseline: 1.7013x; 1.2326x over previous
//
#include <hip/hip_runtime.h>
#include <hip/hip_fp16.h>

#define Bsz 256
#define Nn  1152
#define Kk  10
#define NT  576      // 9 waves
#define NW  9
#define SJ  1154     // uint2 stride per o-pair row: 2*1154 mod 32 = 4 -> 8 distinct bank-pairs

#define W_ELEMS (Kk*Nn*128)   // 2949120
#define U_ELEMS (Bsz*Nn*8)    // 2359296

__device__ __forceinline__ unsigned pkh2(float x, float y) {
    __half2 h = __floats2half2_rn(x, y);
    return *reinterpret_cast<unsigned*>(&h);
}
__device__ __forceinline__ float2 uph2(unsigned v) {
    __half2 h;
    *reinterpret_cast<unsigned*>(&h) = v;
    return __half22float2(h);
}
__device__ __forceinline__ void up8(const uint4 q, float f[8]) {
    float2 a = uph2(q.x), b = uph2(q.y), c = uph2(q.z), d = uph2(q.w);
    f[0]=a.x; f[1]=a.y; f[2]=b.x; f[3]=b.y; f[4]=c.x; f[5]=c.y; f[6]=d.x; f[7]=d.y;
}

// fp32 -> fp16 conversion of W then u into workspace (8 elems/thread)
__global__ void cvt_kernel(const float* __restrict__ W, const float* __restrict__ u,
                           __half2* __restrict__ Wh, __half2* __restrict__ uh) {
    const int idx = blockIdx.x * blockDim.x + threadIdx.x;
    const int wg = W_ELEMS / 8;            // 368640
    const float4* p;
    __half2* o;
    if (idx < wg) {
        p = (const float4*)W + (size_t)idx * 2;
        o = Wh + (size_t)idx * 4;
    } else {
        const int j = idx - wg;            // < 294912
        p = (const float4*)u + (size_t)j * 2;
        o = uh + (size_t)j * 4;
    }
    const float4 a = p[0], b = p[1];
    o[0] = __floats2half2_rn(a.x, a.y);
    o[1] = __floats2half2_rn(a.z, a.w);
    o[2] = __floats2half2_rn(b.x, b.y);
    o[3] = __floats2half2_rn(b.z, b.w);
}

// One block per (bg, k): b-pair b0,b0+1. u_hat fp16 in LDS (b0/b1 interleaved
// uint2, stride SJ). Routing: e-trick softmax (unnormalized exp in cS2,
// denominator reduced in redS col 16) -> 11 barriers total.
template<bool HALF>
__global__ __launch_bounds__(NT, 2)
void digitcaps_kernel(const float* __restrict__ u32, const float* __restrict__ W32,
                      const __half* __restrict__ uh, const __half* __restrict__ Wh,
                      float* __restrict__ out)
{
    const int t    = threadIdx.x;
    const int lane = t & 63;
    const int wav  = t >> 6;
    const int bg   = blockIdx.x;     // 0..127
    const int k    = blockIdx.y;     // 0..9
    const int b0   = bg * 2;

    __shared__ uint2    uhS[8 * SJ];        // 73856 B
    __shared__ unsigned cS2[Nn];            // 4608 B  half2(e_b0, e_b1) per n
    __shared__ float    redS[2 * NW * 17];  // 1224 B  [b][wav][16 s-cols + d]
    __shared__ __align__(16) float vS[32];  // 128 B
    __shared__ float    mS[2];              // 8 B
    // total 79824 B -> 2 blocks/CU

    // ---------------- Phase 1: u_hat = u . W ----------------
    {
        const int oh   = t & 1;
        const int nsub = t >> 1;
        for (int r = 0; r < 4; ++r) {
            const int n = r * 288 + nsub;
            float ua[8], ub[8];
            if (HALF) {
                const uint4 qa = *(const uint4*)(uh + ((size_t)b0 * Nn + n) * 8);
                const uint4 qb = *(const uint4*)(uh + ((size_t)(b0 + 1) * Nn + n) * 8);
                up8(qa, ua); up8(qb, ub);
            } else {
                const float4* up0 = (const float4*)(u32 + ((size_t)b0 * Nn + n) * 8);
                const float4* up1 = (const float4*)(u32 + ((size_t)(b0 + 1) * Nn + n) * 8);
                const float4 x0 = up0[0], x1 = up0[1];
                const float4 y0 = up1[0], y1 = up1[1];
                ua[0]=x0.x; ua[1]=x0.y; ua[2]=x0.z; ua[3]=x0.w;
                ua[4]=x1.x; ua[5]=x1.y; ua[6]=x1.z; ua[7]=x1.w;
                ub[0]=y0.x; ub[1]=y0.y; ub[2]=y0.z; ub[3]=y0.w;
                ub[4]=y1.x; ub[5]=y1.y; ub[6]=y1.z; ub[7]=y1.w;
            }
            float a0[8], a1[8];
            #pragma unroll
            for (int o = 0; o < 8; ++o) { a0[o] = 0.f; a1[o] = 0.f; }
            #pragma unroll
            for (int i = 0; i < 8; ++i) {
                float wv[8];
                if (HALF) {
                    const uint4 qw = *(const uint4*)(Wh + ((size_t)(k * Nn + n)) * 128 + i * 16 + oh * 8);
                    up8(qw, wv);
                } else {
                    const float4* wp = (const float4*)(W32 + ((size_t)k * Nn + n) * 128) + oh * 2 + i * 4;
                    const float4 w0 = wp[0], w1 = wp[1];
                    wv[0]=w0.x; wv[1]=w0.y; wv[2]=w0.z; wv[3]=w0.w;
                    wv[4]=w1.x; wv[5]=w1.y; wv[6]=w1.z; wv[7]=w1.w;
                }
                const float x = ua[i], y = ub[i];
                #pragma unroll
                for (int o = 0; o < 8; ++o) { a0[o] += x * wv[o]; a1[o] += y * wv[o]; }
            }
            #pragma unroll
            for (int jj = 0; jj < 4; ++jj) {
                const int j = oh * 4 + jj;
                uhS[j * SJ + n] = make_uint2(pkh2(a0[2*jj], a0[2*jj+1]),
                                             pkh2(a1[2*jj], a1[2*jj+1]));
            }
        }
    }
    __syncthreads();

    // ---------------- Phase 2: routing ----------------
    float lg0[2] = {0.f, 0.f}, lg1[2] = {0.f, 0.f};
    float v0[16], v1[16];
    const int j_s = lane & 7;
    const int g_s = lane >> 3;

    for (int it = 0; it < 3; ++it) {
        if (it > 0) {
            // ---- a-scan: logits += u_hat . v (rows owned: n = t, t+NT) ----
            #pragma unroll
            for (int r = 0; r < 2; ++r) {
                const int n = t + r * NT;
                float acc0 = 0.f, acc1 = 0.f;
                #pragma unroll
                for (int j = 0; j < 8; ++j) {
                    const uint2 q = uhS[j * SJ + n];
                    const float2 f0 = uph2(q.x);
                    const float2 f1 = uph2(q.y);
                    acc0 += f0.x * v0[2*j] + f0.y * v0[2*j+1];
                    acc1 += f1.x * v1[2*j] + f1.y * v1[2*j+1];
                }
                lg0[r] += acc0;
                lg1[r] += acc1;
            }
            // ---- block max per b ----
            float m0 = fmaxf(lg0[0], lg0[1]);
            float m1 = fmaxf(lg1[0], lg1[1]);
            #pragma unroll
            for (int off = 1; off <= 32; off <<= 1) {
                m0 = fmaxf(m0, __shfl_xor(m0, off));
                m1 = fmaxf(m1, __shfl_xor(m1, off));
            }
            if (lane == 0) { redS[wav] = m0; redS[NW + wav] = m1; }  // scratch use
            __syncthreads();
            if (t < 2) {
                float m = redS[t * NW];
                for (int w = 1; w < NW; ++w) m = fmaxf(m, redS[t * NW + w]);
                mS[t] = m;
            }
            __syncthreads();
            m0 = mS[0]; m1 = mS[1];
            // ---- unnormalized e -> cS2 ----
            const float e00 = __expf(lg0[0] - m0), e01 = __expf(lg0[1] - m0);
            const float e10 = __expf(lg1[0] - m1), e11 = __expf(lg1[1] - m1);
            cS2[t]      = pkh2(e00, e10);
            cS2[t + NT] = pkh2(e01, e11);
            __syncthreads();
        }

        // ---- s-scan: numerator and denominator together ----
        float2 sp0 = {0.f, 0.f}, sp1 = {0.f, 0.f};
        float dp0 = 0.f, dp1 = 0.f;
        #pragma unroll
        for (int cc = 0; cc < 16; ++cc) {
            const int n = cc * 72 + wav * 8 + g_s;
            float c0, c1;
            if (it == 0) { c0 = 1.f; c1 = 1.f; }
            else { const float2 c2 = uph2(cS2[n]); c0 = c2.x; c1 = c2.y; }
            const uint2 q = uhS[j_s * SJ + n];
            const float2 f0 = uph2(q.x);
            const float2 f1 = uph2(q.y);
            sp0.x += c0 * f0.x; sp0.y += c0 * f0.y;
            sp1.x += c1 * f1.x; sp1.y += c1 * f1.y;
            dp0 += c0; dp1 += c1;
        }
        #pragma unroll
        for (int off = 8; off <= 32; off <<= 1) {
            sp0.x += __shfl_xor(sp0.x, off);
            sp0.y += __shfl_xor(sp0.y, off);
            sp1.x += __shfl_xor(sp1.x, off);
            sp1.y += __shfl_xor(sp1.y, off);
            dp0   += __shfl_xor(dp0,   off);
            dp1   += __shfl_xor(dp1,   off);
        }
        if (lane < 8) {
            redS[(0*NW + wav)*17 + 2*j_s    ] = sp0.x;
            redS[(0*NW + wav)*17 + 2*j_s + 1] = sp0.y;
            redS[(1*NW + wav)*17 + 2*j_s    ] = sp1.x;
            redS[(1*NW + wav)*17 + 2*j_s + 1] = sp1.y;
        }
        if (lane == 0) {
            redS[(0*NW + wav)*17 + 16] = dp0;
            redS[(1*NW + wav)*17 + 16] = dp1;
        }
        __syncthreads();

        // ---- finalize s/d + squash on wave 0 ----
        if (t < 32) {
            const int b = t >> 4, o = t & 15;
            float s = 0.f, d = 0.f;
            #pragma unroll
            for (int w = 0; w < NW; ++w) {
                s += redS[(b*NW + w)*17 + o];
                d += redS[(b*NW + w)*17 + 16];
            }
            s /= d;
            float s2 = s * s;
            #pragma unroll
            for (int off = 1; off <= 8; off <<= 1) s2 += __shfl_xor(s2, off);
            const float scale = (s2 / (1.f + s2)) * rsqrtf(fmaxf(s2, 1e-30f));
            const float v = s * scale;
            vS[b*16 + o] = v;
            if (it == 2) out[((size_t)k * Bsz + b0 + b) * 16 + o] = v;
        }
        if (it == 2) break;
        __syncthreads();

        // ---- broadcast v to registers ----
        {
            const float4* vp = (const float4*)vS;
            #pragma unroll
            for (int q4 = 0; q4 < 4; ++q4) {
                *(float4*)&v0[4*q4] = vp[q4];
                *(float4*)&v1[4*q4] = vp[4 + q4];
            }
        }
    }
}

extern "C" void kernel_launch(void* const* d_in, const int* in_sizes, int n_in,
                              void* d_out, int out_size, void* d_ws, size_t ws_size,
                              hipStream_t stream) {
    const float* u = (const float*)d_in[0];
    const float* W = (const float*)d_in[1];
    float* out = (float*)d_out;
    const size_t need = (size_t)(W_ELEMS + U_ELEMS) * sizeof(__half);
    if (ws_size >= need) {
        __half* Wh = (__half*)d_ws;
        __half* uh = (__half*)((char*)d_ws + (size_t)W_ELEMS * sizeof(__half));
        cvt_kernel<<<dim3((W_ELEMS + U_ELEMS) / 8 / 256), dim3(256), 0, stream>>>(
            W, u, (__half2*)Wh, (__half2*)uh);
        digitcaps_kernel<true><<<dim3(128, 10), dim3(NT), 0, stream>>>(
            nullptr, nullptr, uh, Wh, out);
    } else {
        digitcaps_kernel<false><<<dim3(128, 10), dim3(NT), 0, stream>>>(
            u, W, nullptr, nullptr, out);
    }
}